// Round 6
// baseline (602.819 us; speedup 1.0000x reference)
//
#include <hip/hip_runtime.h>
#include <math.h>

#define BB 4
#define DD 31

typedef _Float16 half8 __attribute__((ext_vector_type(8)));
typedef float f32x4 __attribute__((ext_vector_type(4)));

__device__ __forceinline__ int swz(int b) { return b ^ (((b >> 7) & 7) << 4); }
__device__ __forceinline__ half8 ldswz(const _Float16* lin, int byteoff) {
    return *(const half8*)((const char*)lin + swz(byteoff));
}
__device__ __forceinline__ void stswz(_Float16* lin, int byteoff, half8 v) {
    *(half8*)((char*)lin + swz(byteoff)) = v;
}
__device__ __forceinline__ float fast_tanh(float y) {
    float e = __expf(2.f * y);
    return 1.f - 2.f * __builtin_amdgcn_rcpf(e + 1.f);
}
__device__ __forceinline__ float fast_sigmoid(float y) {
    return __builtin_amdgcn_rcpf(1.f + __expf(-y));
}

// ---------------- prep kernels ----------------

__global__ void bnprep(const float* __restrict__ bn, int C, float* __restrict__ sh) {
    int c = threadIdx.x;
    if (c >= C) return;
    float g = bn[c], b = bn[C + c], m = bn[2 * C + c], v = bn[3 * C + c];
    sh[c] = b - m * (g * rsqrtf(v + 1e-5f));
}

// dst[q][ko][n][c16][ki]; co = n*(COUT/2) + q*16 + c16; k = ko*32+ki = tap*CIN+ci
// tr=0: W = src[co][ci][tap]; tr=1 (deconv): W = src[ci][co][26-tap]. BN scale folded.
__global__ void wprep(const float* __restrict__ src, const float* __restrict__ bn,
                      _Float16* __restrict__ dst, int CIN, int COUT, int KS, int CS, int tr) {
    int idx = blockIdx.x * 256 + threadIdx.x;
    int total = CS * KS * 1024;
    if (idx >= total) return;
    int ki = idx & 31;
    int c16 = (idx >> 5) & 15;
    int n = (idx >> 9) & 1;
    int ko = (idx >> 10) % KS;
    int q = idx / (KS * 1024);
    int co = n * (COUT / 2) + q * 16 + c16;
    int k = ko * 32 + ki;
    float v = 0.f;
    if (k < 27 * CIN) {
        int tap = k / CIN, ci = k % CIN;
        v = tr ? src[((size_t)ci * COUT + co) * 27 + (26 - tap)]
               : src[((size_t)co * CIN + ci) * 27 + tap];
        v *= bn[co] * rsqrtf(bn[3 * COUT + co] + 1e-5f);
    }
    dst[idx] = (_Float16)v;
}

// Collapsed upsample-conv weights. dst[q][par][ko][n][c16][ki];
// k = tap*CIN+ci with tap = (kd*2+ih)*2+iw (12 taps). conv layout src[co][ci][27].
__global__ void wprep_up(const float* __restrict__ src, const float* __restrict__ bn,
                         _Float16* __restrict__ dst, int CIN, int COUT, int KS, int CS) {
    int idx = blockIdx.x * 256 + threadIdx.x;
    int total = CS * 4 * KS * 1024;
    if (idx >= total) return;
    int ki = idx & 31;
    int c16 = (idx >> 5) & 15;
    int n = (idx >> 9) & 1;
    int ko = (idx >> 10) % KS;
    int par = (idx / (KS * 1024)) & 3;
    int q = idx / (KS * 4096);
    int co = n * (COUT / 2) + q * 16 + c16;
    int k = ko * 32 + ki;
    int ci = k % CIN, tap = k / CIN;
    int kd = tap >> 2, ih = (tap >> 1) & 1, iw = tap & 1;
    int ph = par >> 1, pw = par & 1;
    const float c[2][2][3] = {{{1, 0, 0}, {0, 1, 1}}, {{1, 1, 0}, {0, 0, 1}}};
    float v = 0.f;
    for (int kh = 0; kh < 3; ++kh)
        for (int kw = 0; kw < 3; ++kw)
            v += c[ph][ih][kh] * c[pw][iw][kw] *
                 src[((size_t)co * CIN + ci) * 27 + kd * 9 + kh * 3 + kw];
    v *= bn[co] * rsqrtf(bn[3 * COUT + co] + 1e-5f);
    dst[idx] = (_Float16)v;
}

// x [4][64][31][1024] f32 NCDHW -> xf [4*31][1024][64] f16 NDHWC
__global__ __launch_bounds__(256) void xconv(const float* __restrict__ src,
                                             _Float16* __restrict__ dst) {
    int idx = blockIdx.x * 256 + threadIdx.x;
    if (idx >= 4 * 31 * 1024 * 8) return;
    int cb = idx & 7;
    int pos = (idx >> 3) & 1023;
    int bd = idx >> 13;
    int d = bd % 31, b = bd / 31;
    half8 v;
#pragma unroll
    for (int j = 0; j < 8; ++j)
        v[j] = (_Float16)src[(((size_t)b * 64 + cb * 8 + j) * 31 + d) * 1024 + pos];
    *(half8*)(dst + ((size_t)bd * 1024 + pos) * 64 + cb * 8) = v;
}

// ============ fused conv + BN + act + qrnn-scan (non-upsample; layers 2,4) ============
// Block: 16(w) x 4*NF(h) tile, hidden-channel slice q (CS blocks cover COUT), one b.
// d-loop with 4-slot LDS plane ring; lead plane (d+2*dir) loaded to regs before
// compute, ds_written after (async-stage split). Thread-local scan state:
// acc[f][0]=z (co=q*16+col), acc[f][1]=gate (co=HID+q*16+col), same positions.
template <int CIN, int S, int HID, int KS, int NF, int CS, int REV, int LAST>
__global__ __launch_bounds__(256, 2) void fconv(
    const _Float16* __restrict__ inp,   // [B*DD][S][S][CIN] f16
    const _Float16* __restrict__ wq,    // [CS][KS][2][16][32] f16
    const float* __restrict__ bnsh,     // [2*HID]
    const float* __restrict__ xs,       // [B][HID][DD][S][S] f32 (mid) or null
    _Float16* __restrict__ hout,        // [B*DD][S*S][HID] f16 (mid)
    float* __restrict__ fout) {         // [B][HID][DD][S*S] f32 (last)

    constexpr int IW = 18;
    constexpr int TH = 4 * NF;
    constexpr int IHP = TH + 2;
    constexpr int NC8 = CIN / 8;
    constexpr int P8 = IHP * IW * NC8;
    constexpr int NST = (P8 + 255) / 256;
    constexpr int PLANEB = IHP * IW * CIN * 2;

    __shared__ __align__(16) _Float16 lin[4 * IHP * IW * CIN];

    const int tid = threadIdx.x;
    const int lane = tid & 63;
    const int wv = tid >> 6;
    const int col = lane & 15;
    const int grp = lane >> 4;

    const int w0 = blockIdx.x * 16;
    const int h0 = blockIdx.y * TH;
    const int b = blockIdx.z / CS;
    const int q = blockIdx.z % CS;
    const size_t bbase = (size_t)b * DD;

    const float shz = bnsh[q * 16 + col];
    const float shf = bnsh[HID + q * 16 + col];
    const int hc = q * 16 + col;
    const _Float16* wqb = wq + (size_t)q * KS * 1024;

    auto stage_now = [&](int dz) {
        int slot = (dz + 8) & 3;
        for (int idx = tid; idx < P8; idx += 256) {
            int c8 = idx % NC8;
            int pos = idx / NC8;
            int ih = pos / IW, iw = pos % IW;
            int gh = h0 - 1 + ih, gw = w0 - 1 + iw;
            half8 v = {0, 0, 0, 0, 0, 0, 0, 0};
            if ((unsigned)dz < (unsigned)DD && (unsigned)gh < (unsigned)S &&
                (unsigned)gw < (unsigned)S)
                v = *(const half8*)(inp + (((bbase + dz) * S + gh) * S + gw) * CIN + c8 * 8);
            stswz(lin, slot * PLANEB + (pos * CIN + c8 * 8) * 2, v);
        }
    };

    constexpr int dir = REV ? -1 : 1;
    const int d0 = REV ? DD - 1 : 0;
    stage_now(d0 - dir);
    stage_now(d0);
    stage_now(d0 + dir);
    __syncthreads();

    float hst[NF][4];
#pragma unroll
    for (int f = 0; f < NF; ++f)
#pragma unroll
        for (int r = 0; r < 4; ++r) hst[f][r] = 0.f;

    for (int t = 0; t < DD; ++t) {
        const int d = d0 + dir * t;
        const int dzl = d + 2 * dir;

        // issue lead-plane global loads (kept in regs across compute)
        half8 sv[NST];
#pragma unroll
        for (int i = 0; i < NST; ++i) {
            int idx = tid + i * 256;
            half8 v = {0, 0, 0, 0, 0, 0, 0, 0};
            if (idx < P8) {
                int c8 = idx % NC8;
                int pos = idx / NC8;
                int ih = pos / IW, iw = pos % IW;
                int gh = h0 - 1 + ih, gw = w0 - 1 + iw;
                if ((unsigned)dzl < (unsigned)DD && (unsigned)gh < (unsigned)S &&
                    (unsigned)gw < (unsigned)S)
                    v = *(const half8*)(inp +
                        (((bbase + dzl) * S + gh) * S + gw) * CIN + c8 * 8);
            }
            sv[i] = v;
        }

        // conv for output plane d (reads slots of planes d-1,d,d+1)
        f32x4 acc[NF][2];
#pragma unroll
        for (int f = 0; f < NF; ++f) {
            acc[f][0] = {0.f, 0.f, 0.f, 0.f};
            acc[f][1] = {0.f, 0.f, 0.f, 0.f};
        }
#pragma unroll
        for (int ko = 0; ko < KS; ++ko) {
            int kd, kh, kw, ci;
            if (CIN >= 32) {
                int tap = (ko * 32) / CIN;
                kd = tap / 9; kh = (tap / 3) % 3; kw = tap % 3;
                ci = (ko * 32) % CIN + grp * 8;
            } else {                                // CIN==16: 2 taps per k-step
                int t0 = (2 * ko < 27) ? 2 * ko : 26;
                int t1 = (2 * ko + 1 < 27) ? 2 * ko + 1 : 26;
                int hi = grp >> 1;
                kd = hi ? t1 / 9 : t0 / 9;
                kh = hi ? (t1 / 3) % 3 : (t0 / 3) % 3;
                kw = hi ? t1 % 3 : t0 % 3;
                ci = (grp & 1) * 8;
            }
            int slot = (d + kd + 7) & 3;            // plane d+kd-1
            int iw = col + kw;
            half8 a[NF];
#pragma unroll
            for (int f = 0; f < NF; ++f)
                a[f] = ldswz(lin, slot * PLANEB +
                             (((wv * NF + f + kh) * IW + iw) * CIN + ci) * 2);
            half8 bf0 = *(const half8*)(wqb + ko * 1024 + col * 32 + grp * 8);
            half8 bf1 = *(const half8*)(wqb + ko * 1024 + 512 + col * 32 + grp * 8);
#pragma unroll
            for (int f = 0; f < NF; ++f) {
                acc[f][0] = __builtin_amdgcn_mfma_f32_16x16x32_f16(a[f], bf0, acc[f][0], 0, 0, 0);
                acc[f][1] = __builtin_amdgcn_mfma_f32_16x16x32_f16(a[f], bf1, acc[f][1], 0, 0, 0);
            }
        }

        // commit lead plane to LDS (slot holds plane d-2*dir: not read by this d)
        {
            int slot = (dzl + 8) & 3;
#pragma unroll
            for (int i = 0; i < NST; ++i) {
                int idx = tid + i * 256;
                if (idx < P8) {
                    int c8 = idx % NC8;
                    int pos = idx / NC8;
                    stswz(lin, slot * PLANEB + (pos * CIN + c8 * 8) * 2, sv[i]);
                }
            }
        }

        // BN + act + scan + store
#pragma unroll
        for (int f = 0; f < NF; ++f) {
            int h = h0 + wv * NF + f;
#pragma unroll
            for (int r = 0; r < 4; ++r) {
                int w = w0 + grp * 4 + r;
                size_t sp = (size_t)h * S + w;
                float z = fast_tanh(acc[f][0][r] + shz);
                float fg = fast_sigmoid(acc[f][1][r] + shf);
                hst[f][r] = fg * hst[f][r] + (1.f - fg) * z;
                if (LAST) {
                    fout[(((size_t)b * HID + hc) * DD + d) * ((size_t)S * S) + sp] = hst[f][r];
                } else {
                    float xv = xs[(((size_t)b * HID + hc) * DD + d) * ((size_t)S * S) + sp];
                    hout[((bbase + d) * ((size_t)S * S) + sp) * HID + hc] =
                        (_Float16)(hst[f][r] + xv);
                }
            }
        }
        __syncthreads();
    }
}

// ============ fused collapsed-upsample conv + scan (layers 1,3) ============
// Wave = output parity (ph,pw); block covers 32(w) x 2*NF(h) output, input patch
// at original resolution [4 slots][NF+2][18][CIN]. K = CIN*12 collapsed taps.
template <int CIN, int S, int HID, int KS, int NF, int CS, int REV, int LAST>
__global__ __launch_bounds__(256, 2) void fconv_up(
    const _Float16* __restrict__ inp,   // [B*DD][S/2][S/2][CIN] f16
    const _Float16* __restrict__ wq,    // [CS][4][KS][2][16][32] f16
    const float* __restrict__ bnsh,
    const float* __restrict__ xs,
    _Float16* __restrict__ hout,
    float* __restrict__ fout) {

    constexpr int SIN = S / 2;
    constexpr int IW = 18;
    constexpr int IHP = NF + 2;
    constexpr int NC8 = CIN / 8;
    constexpr int P8 = IHP * IW * NC8;
    constexpr int NST = (P8 + 255) / 256;
    constexpr int PLANEB = IHP * IW * CIN * 2;

    __shared__ __align__(16) _Float16 lin[4 * IHP * IW * CIN];

    const int tid = threadIdx.x;
    const int lane = tid & 63;
    const int wv = tid >> 6;
    const int col = lane & 15;
    const int grp = lane >> 4;
    const int ph = wv >> 1, pw = wv & 1;

    const int bwp = blockIdx.x * 16;    // base w' (orig res)
    const int bhp = blockIdx.y * NF;    // base h'
    const int b = blockIdx.z / CS;
    const int q = blockIdx.z % CS;
    const size_t bbase = (size_t)b * DD;

    const float shz = bnsh[q * 16 + col];
    const float shf = bnsh[HID + q * 16 + col];
    const int hc = q * 16 + col;
    const _Float16* wqb = wq + ((size_t)(q * 4 + wv) * KS) * 1024;

    auto stage_now = [&](int dz) {
        int slot = (dz + 8) & 3;
        for (int idx = tid; idx < P8; idx += 256) {
            int c8 = idx % NC8;
            int pos = idx / NC8;
            int ih = pos / IW, iw = pos % IW;
            int gh = bhp - 1 + ih, gw = bwp - 1 + iw;
            half8 v = {0, 0, 0, 0, 0, 0, 0, 0};
            if ((unsigned)dz < (unsigned)DD && (unsigned)gh < (unsigned)SIN &&
                (unsigned)gw < (unsigned)SIN)
                v = *(const half8*)(inp + (((bbase + dz) * SIN + gh) * SIN + gw) * CIN + c8 * 8);
            stswz(lin, slot * PLANEB + (pos * CIN + c8 * 8) * 2, v);
        }
    };

    constexpr int dir = REV ? -1 : 1;
    const int d0 = REV ? DD - 1 : 0;
    stage_now(d0 - dir);
    stage_now(d0);
    stage_now(d0 + dir);
    __syncthreads();

    float hst[NF][4];
#pragma unroll
    for (int f = 0; f < NF; ++f)
#pragma unroll
        for (int r = 0; r < 4; ++r) hst[f][r] = 0.f;

    for (int t = 0; t < DD; ++t) {
        const int d = d0 + dir * t;
        const int dzl = d + 2 * dir;

        half8 sv[NST];
#pragma unroll
        for (int i = 0; i < NST; ++i) {
            int idx = tid + i * 256;
            half8 v = {0, 0, 0, 0, 0, 0, 0, 0};
            if (idx < P8) {
                int c8 = idx % NC8;
                int pos = idx / NC8;
                int ih = pos / IW, iw = pos % IW;
                int gh = bhp - 1 + ih, gw = bwp - 1 + iw;
                if ((unsigned)dzl < (unsigned)DD && (unsigned)gh < (unsigned)SIN &&
                    (unsigned)gw < (unsigned)SIN)
                    v = *(const half8*)(inp +
                        (((bbase + dzl) * SIN + gh) * SIN + gw) * CIN + c8 * 8);
            }
            sv[i] = v;
        }

        f32x4 acc[NF][2];
#pragma unroll
        for (int f = 0; f < NF; ++f) {
            acc[f][0] = {0.f, 0.f, 0.f, 0.f};
            acc[f][1] = {0.f, 0.f, 0.f, 0.f};
        }
#pragma unroll
        for (int ko = 0; ko < KS; ++ko) {
            int tap = (ko * 32) / CIN;
            int ci = (ko * 32) % CIN + grp * 8;
            int kd = tap >> 2, ihh = (tap >> 1) & 1, iwk = tap & 1;
            int slot = (d + kd + 7) & 3;
            int lcol = col + iwk + pw;
            int row0 = ihh + ph;
            half8 a[NF];
#pragma unroll
            for (int f = 0; f < NF; ++f)
                a[f] = ldswz(lin, slot * PLANEB +
                             ((((row0 + f) * IW) + lcol) * CIN + ci) * 2);
            half8 bf0 = *(const half8*)(wqb + ko * 1024 + col * 32 + grp * 8);
            half8 bf1 = *(const half8*)(wqb + ko * 1024 + 512 + col * 32 + grp * 8);
#pragma unroll
            for (int f = 0; f < NF; ++f) {
                acc[f][0] = __builtin_amdgcn_mfma_f32_16x16x32_f16(a[f], bf0, acc[f][0], 0, 0, 0);
                acc[f][1] = __builtin_amdgcn_mfma_f32_16x16x32_f16(a[f], bf1, acc[f][1], 0, 0, 0);
            }
        }

        {
            int slot = (dzl + 8) & 3;
#pragma unroll
            for (int i = 0; i < NST; ++i) {
                int idx = tid + i * 256;
                if (idx < P8) {
                    int c8 = idx % NC8;
                    int pos = idx / NC8;
                    stswz(lin, slot * PLANEB + (pos * CIN + c8 * 8) * 2, sv[i]);
                }
            }
        }

#pragma unroll
        for (int f = 0; f < NF; ++f) {
            int h = 2 * (bhp + f) + ph;
#pragma unroll
            for (int r = 0; r < 4; ++r) {
                int w = 2 * (bwp + grp * 4 + r) + pw;
                size_t sp = (size_t)h * S + w;
                float z = fast_tanh(acc[f][0][r] + shz);
                float fg = fast_sigmoid(acc[f][1][r] + shf);
                hst[f][r] = fg * hst[f][r] + (1.f - fg) * z;
                if (LAST) {
                    fout[(((size_t)b * HID + hc) * DD + d) * ((size_t)S * S) + sp] = hst[f][r];
                } else {
                    float xv = xs[(((size_t)b * HID + hc) * DD + d) * ((size_t)S * S) + sp];
                    hout[((bbase + d) * ((size_t)S * S) + sp) * HID + hc] =
                        (_Float16)(hst[f][r] + xv);
                }
            }
        }
        __syncthreads();
    }
}

extern "C" void kernel_launch(void* const* d_in, const int* in_sizes, int n_in,
                              void* d_out, int out_size, void* d_ws, size_t ws_size,
                              hipStream_t stream) {
    const float* x   = (const float*)d_in[0];
    const float* xs0 = (const float*)d_in[1];
    const float* xs1 = (const float*)d_in[2];
    const float* xs2 = (const float*)d_in[3];
    const float* w0  = (const float*)d_in[4];
    const float* w1  = (const float*)d_in[5];
    const float* w2  = (const float*)d_in[6];
    const float* w3  = (const float*)d_in[7];
    const float* bn0 = (const float*)d_in[8];
    const float* bn1 = (const float*)d_in[9];
    const float* bn2 = (const float*)d_in[10];
    const float* bn3 = (const float*)d_in[11];
    float* out = (float*)d_out;

    // ---- workspace layout ----
    char* p = (char*)d_ws;
    _Float16* xf   = (_Float16*)p; p += (size_t)124 * 1024 * 64 * 2;    // 16.25 MB
    _Float16* hA   = (_Float16*)p; p += (size_t)124 * 4096 * 32 * 2;    // 32.5 MB (h1+xs2)
    _Float16* hA2  = (_Float16*)p; p += (size_t)124 * 4096 * 32 * 2;    // 32.5 MB (h2+xs1)
    _Float16* hB   = (_Float16*)p; p += (size_t)124 * 16384 * 16 * 2;   // 65 MB   (h3+xs0)
    _Float16* wq0u = (_Float16*)p; p += (size_t)2 * 4 * 24 * 1024 * 2;  // 384 KB
    _Float16* wq1  = (_Float16*)p; p += (size_t)2 * 27 * 1024 * 2;
    _Float16* wq2u = (_Float16*)p; p += (size_t)4 * 12 * 1024 * 2;
    _Float16* wq3  = (_Float16*)p; p += (size_t)14 * 1024 * 2;
    float* sh0 = (float*)p; p += 64 * 4;
    float* sh1 = (float*)p; p += 64 * 4;
    float* sh2 = (float*)p; p += 64 * 4;
    float* sh3 = (float*)p; p += 64 * 4;

    // ---- prep ----
    xconv<<<(4 * 31 * 1024 * 8 + 255) / 256, 256, 0, stream>>>(x, xf);
    wprep_up<<<(2 * 4 * 24 * 1024 + 255) / 256, 256, 0, stream>>>(w0, bn0, wq0u, 64, 64, 24, 2);
    wprep<<<(2 * 27 * 1024 + 255) / 256, 256, 0, stream>>>(w1, bn1, wq1, 32, 64, 27, 2, 1);
    wprep_up<<<(4 * 12 * 1024 + 255) / 256, 256, 0, stream>>>(w2, bn2, wq2u, 32, 32, 12, 1);
    wprep<<<(14 * 1024 + 255) / 256, 256, 0, stream>>>(w3, bn3, wq3, 16, 32, 14, 1, 1);
    bnprep<<<1, 64, 0, stream>>>(bn0, 64, sh0);
    bnprep<<<1, 64, 0, stream>>>(bn1, 64, sh1);
    bnprep<<<1, 64, 0, stream>>>(bn2, 32, sh2);
    bnprep<<<1, 64, 0, stream>>>(bn3, 32, sh3);

    // ---- layer 1: up(x) -> conv w0 (64->64) @64, fwd scan; out hA = h1+xs2 ----
    fconv_up<64, 64, 32, 24, 1, 2, 0, 0><<<dim3(2, 32, BB * 2), 256, 0, stream>>>(
        xf, wq0u, sh0, xs2, hA, nullptr);
    // ---- layer 2: deconv w1 (32->64) @64, rev scan; out hA2 = h2+xs1 ----
    fconv<32, 64, 32, 27, 1, 2, 1, 0><<<dim3(4, 16, BB * 2), 256, 0, stream>>>(
        hA, wq1, sh1, xs1, hA2, nullptr);
    // ---- layer 3: up -> conv w2 (32->32) @128, fwd scan; out hB = h3+xs0 ----
    fconv_up<32, 128, 16, 12, 2, 1, 0, 0><<<dim3(4, 32, BB), 256, 0, stream>>>(
        hA2, wq2u, sh2, xs0, hB, nullptr);
    // ---- layer 4: deconv w3 (16->32) @128, rev scan; out fp32 NCDHW ----
    fconv<16, 128, 16, 14, 2, 1, 1, 1><<<dim3(8, 16, BB), 256, 0, stream>>>(
        hB, wq3, sh3, nullptr, nullptr, out);
}